// Round 9
// baseline (445.389 us; speedup 1.0000x reference)
//
#include <hip/hip_runtime.h>
#include <stdint.h>

// SpatialHyperedgeMP: out = ((inc + head) @ cur) / rowsum(inc + head)
//   head_ij = (inc_ij > 0) / sqrt(cnt_i),  cnt_i = #positives in row i
// Decomposition (single fused pass over inc):
//   out[i] = (inc@cur + invs_i * (mask@cur)) * rdeg_i
//   invs_i = 1/sqrt(cnt_i),  rdeg_i = 1/(s1_i + sqrt(cnt_i))
//
// R9: barrier-free dataflow GEMM. R3-R8 post-mortem: every LDS-staged variant
// is stall-bound on the per-tile intra-block barrier (all pipes <=40%). Now:
//   - A loaded per-wave DIRECTLY from global in MFMA fragment layout
//     (lane r=lane&15,q=lane>>4 reads row brow+r, k=q*8+kh*32+e — the exact
//     mapping verified via LDS in R5-R8), fp64-exact stats + mask frag built
//     in-register. B frags direct from ws (verified bOff mapping).
//   - ZERO LDS, ZERO barriers. Waves fully independent; stats reduced by
//     shfl at the end. 4 blocks/CU = 4 waves/SIMD hide all latency.
//   - Register plan ~110 (no B double-buffer, no LDS path) -> fits the
//     launch_bounds(256,4) 128-VGPR cap WITHOUT spilling (R8 lesson).
// Swizzle: nt=id&1 -> each XCD streams one 4MB B chunk (L2-resident);
// nt-partners of an mt are adjacent ids on paired XCDs -> L3 dedups A.
//
// ws usage: 8MB B chunks only.

#define NROWS 8192
#define DDIM  512

typedef float f32x4 __attribute__((ext_vector_type(4)));
typedef short s16x8 __attribute__((ext_vector_type(8)));

__device__ __forceinline__ unsigned short f2bf(float f) {
  union { float f; unsigned int u; } c; c.f = f;
  unsigned int u = c.u;
  unsigned int r = u + 0x7FFFu + ((u >> 16) & 1u);
  return (unsigned short)(r >> 16);
}

// ---------------- kernel 1: B prep (cur -> bf16 chunked-transposed) ----------------
// chunk layout: nt(2) x kt(128): 32KB chunk = [kg=8][nn=256][e=8] bf16
__global__ __launch_bounds__(256) void bprep_kernel(const float* __restrict__ cur,
                                                    unsigned char* __restrict__ bws) {
  int idx = blockIdx.x * 256 + threadIdx.x;  // 0..524287
  int n = idx & 511;
  int kg9 = idx >> 9;  // 0..1023
  int kt = kg9 >> 3;
  int kg = kg9 & 7;
  int k0 = kt * 64 + kg * 8;
  union { unsigned short h[8]; uint4 q; } u;
#pragma unroll
  for (int e = 0; e < 8; ++e)
    u.h[e] = f2bf(cur[(size_t)(k0 + e) * DDIM + n]);
  int nt = n >> 8, nn = n & 255;
  size_t off = ((size_t)(nt * 128 + kt) << 15) + ((size_t)kg << 12) + ((size_t)nn << 4);
  *(uint4*)(bws + off) = u.q;
}

// ---------------- kernel 2: fused stats + dual-GEMM, barrier-free ----------------
// BM=16 BN=256 BK=64, 256 threads = 4 waves (1M x 4N), wave tile 16x64.
// All 4 waves read the same 4KB A tile (L1-dedup'd); each owns 64 cols of B.

#define MFMA __builtin_amdgcn_mfma_f32_16x16x32_bf16

__global__ __launch_bounds__(256, 4) void gemm_kernel(const float* __restrict__ inc,
                                                      const unsigned char* __restrict__ bws,
                                                      float* __restrict__ out) {
  const int tid = threadIdx.x;
  const int lane = tid & 63;
  const int wv = tid >> 6;       // 0..3
  const int r = lane & 15;
  const int q = lane >> 4;       // 0..3

  const int id = blockIdx.x;     // 0..1023
  const int nt = id & 1;         // XCD parity -> fixed 4MB B chunk per XCD
  const int mt = id >> 1;        // 0..511; partners (nt=0/1) are adjacent ids
  const int brow = mt * 16;
  const int bcol = nt * 256 + wv * 64;

  // A: lane reads row brow+r, fp32 k = kt*64 + kh*32 + q*8 + e  (frag layout)
  const char* gA = (const char*)(inc + (size_t)(brow + r) * NROWS + q * 8);
  // B: frag (kh,cg) at chunk(nt,kt) + (kh*4+q)*4096 + (wv*64+cg*16+r)*16
  const unsigned char* gB0 = bws + ((size_t)nt << 22) + (q << 12) + ((wv * 64 + r) << 4);
  const unsigned char* gB1 = gB0 + 16384;

  f32x4 acc1[4], acc2[4];
#pragma unroll
  for (int b = 0; b < 4; ++b) {
    acc1[b] = (f32x4){0.f, 0.f, 0.f, 0.f};
    acc2[b] = (f32x4){0.f, 0.f, 0.f, 0.f};
  }

  double s1 = 0.0;
  int cnt = 0;
  float4 x0, x1, x2, x3, y0, y1, y2, y3;

#define LOADA(a0, a1, a2, a3, KT) do {                                                    \
    const char* _p = gA + (size_t)(KT) * 256;                                             \
    a0 = *(const float4*)(_p);                                                            \
    a1 = *(const float4*)(_p + 16);                                                       \
    a2 = *(const float4*)(_p + 128);                                                      \
    a3 = *(const float4*)(_p + 144);                                                      \
  } while (0)

// build bf16 frag + mask frag from 8 raw fp32 (one kh half)
#define MKFRAGS(lo, hi, AF, MF) do {                                                      \
    union { unsigned u[4]; s16x8 s; } _a, _m;                                             \
    asm("v_cvt_pk_bf16_f32 %0, %1, %2" : "=v"(_a.u[0]) : "v"(lo.x), "v"(lo.y));           \
    asm("v_cvt_pk_bf16_f32 %0, %1, %2" : "=v"(_a.u[1]) : "v"(lo.z), "v"(lo.w));           \
    asm("v_cvt_pk_bf16_f32 %0, %1, %2" : "=v"(_a.u[2]) : "v"(hi.x), "v"(hi.y));           \
    asm("v_cvt_pk_bf16_f32 %0, %1, %2" : "=v"(_a.u[3]) : "v"(hi.z), "v"(hi.w));           \
    _m.u[0] = (lo.x > 0.f ? 0x3F80u : 0u) | (lo.y > 0.f ? 0x3F800000u : 0u);              \
    _m.u[1] = (lo.z > 0.f ? 0x3F80u : 0u) | (lo.w > 0.f ? 0x3F800000u : 0u);              \
    _m.u[2] = (hi.x > 0.f ? 0x3F80u : 0u) | (hi.y > 0.f ? 0x3F800000u : 0u);              \
    _m.u[3] = (hi.z > 0.f ? 0x3F80u : 0u) | (hi.w > 0.f ? 0x3F800000u : 0u);              \
    AF = _a.s; MF = _m.s;                                                                 \
  } while (0)

// one kh half: 4 B-frag loads + 8 MFMA
#define HALF(AF, MF, PB, KT) do {                                                         \
    const unsigned char* _b = (PB) + ((size_t)(KT) << 15);                                \
    s16x8 _b0 = *(const s16x8*)(_b);                                                      \
    s16x8 _b1 = *(const s16x8*)(_b + 256);                                                \
    s16x8 _b2 = *(const s16x8*)(_b + 512);                                                \
    s16x8 _b3 = *(const s16x8*)(_b + 768);                                                \
    acc1[0] = MFMA(AF, _b0, acc1[0], 0, 0, 0); acc2[0] = MFMA(MF, _b0, acc2[0], 0, 0, 0); \
    acc1[1] = MFMA(AF, _b1, acc1[1], 0, 0, 0); acc2[1] = MFMA(MF, _b1, acc2[1], 0, 0, 0); \
    acc1[2] = MFMA(AF, _b2, acc1[2], 0, 0, 0); acc2[2] = MFMA(MF, _b2, acc2[2], 0, 0, 0); \
    acc1[3] = MFMA(AF, _b3, acc1[3], 0, 0, 0); acc2[3] = MFMA(MF, _b3, acc2[3], 0, 0, 0); \
  } while (0)

#define TILE(a0, a1, a2, a3, KT) do {                                                     \
    float _t0 = (a0.x + a0.y) + (a0.z + a0.w);                                            \
    float _t1 = (a1.x + a1.y) + (a1.z + a1.w);                                            \
    float _t2 = (a2.x + a2.y) + (a2.z + a2.w);                                            \
    float _t3 = (a3.x + a3.y) + (a3.z + a3.w);                                            \
    s1 += (double)_t0; s1 += (double)_t1; s1 += (double)_t2; s1 += (double)_t3;           \
    cnt += (a0.x > 0.f) + (a0.y > 0.f) + (a0.z > 0.f) + (a0.w > 0.f)                      \
         + (a1.x > 0.f) + (a1.y > 0.f) + (a1.z > 0.f) + (a1.w > 0.f)                      \
         + (a2.x > 0.f) + (a2.y > 0.f) + (a2.z > 0.f) + (a2.w > 0.f)                      \
         + (a3.x > 0.f) + (a3.y > 0.f) + (a3.z > 0.f) + (a3.w > 0.f);                     \
    s16x8 _af0, _mf0, _af1, _mf1;                                                         \
    MKFRAGS(a0, a1, _af0, _mf0);                                                          \
    MKFRAGS(a2, a3, _af1, _mf1);                                                          \
    __builtin_amdgcn_s_setprio(1);                                                        \
    HALF(_af0, _mf0, gB0, KT);                                                            \
    HALF(_af1, _mf1, gB1, KT);                                                            \
    __builtin_amdgcn_s_setprio(0);                                                        \
  } while (0)

  // ---- K loop: raw A prefetched 1 tile ahead, no barriers anywhere ----
  LOADA(x0, x1, x2, x3, 0);
  for (int kt = 0; kt < 126; kt += 2) {
    LOADA(y0, y1, y2, y3, kt + 1);
    TILE(x0, x1, x2, x3, kt);
    LOADA(x0, x1, x2, x3, kt + 2);
    TILE(y0, y1, y2, y3, kt + 1);
  }
  LOADA(y0, y1, y2, y3, 127);
  TILE(x0, x1, x2, x3, 126);
  TILE(y0, y1, y2, y3, 127);

  // ---- stats: reduce over the 4 lanes sharing a row (lanes r, r+16, r+32, r+48)
  s1 += __shfl_xor(s1, 16);
  s1 += __shfl_xor(s1, 32);
  cnt += __shfl_xor(cnt, 16);
  cnt += __shfl_xor(cnt, 32);
  double sq = sqrt((double)cnt);
  float invsL = (cnt > 0) ? (float)(1.0 / sq) : 0.0f;
  float rdegL = (float)(1.0 / (s1 + sq));

  // ---- epilogue: lane needs rows q*4+j; lane (q*4+j) holds that row's stats
  float iv[4], rd[4];
#pragma unroll
  for (int j = 0; j < 4; ++j) {
    iv[j] = __shfl(invsL, q * 4 + j);
    rd[j] = __shfl(rdegL, q * 4 + j);
  }
#pragma unroll
  for (int cg = 0; cg < 4; ++cg) {
#pragma unroll
    for (int j = 0; j < 4; ++j) {
      out[(size_t)(brow + q * 4 + j) * DDIM + bcol + cg * 16 + r] =
          (acc1[cg][j] + iv[j] * acc2[cg][j]) * rd[j];
    }
  }
#undef LOADA
#undef MKFRAGS
#undef HALF
#undef TILE
}

extern "C" void kernel_launch(void* const* d_in, const int* in_sizes, int n_in,
                              void* d_out, int out_size, void* d_ws, size_t ws_size,
                              hipStream_t stream) {
  const float* cur = (const float*)d_in[0];          // [8192, 512] fp32
  const float* incm = (const float*)d_in[1];         // [8192, 8192] fp32
  float* out = (float*)d_out;                        // [8192, 512] fp32
  unsigned char* bws = (unsigned char*)d_ws;         // 8MB B chunks

  hipLaunchKernelGGL(bprep_kernel, dim3((NROWS * DDIM / 8) / 256), dim3(256), 0, stream,
                     cur, bws);
  hipLaunchKernelGGL(gemm_kernel, dim3(1024), dim3(256), 0, stream, incm, bws, out);
}

// Round 10
// 222.064 us; speedup vs baseline: 2.0057x; 2.0057x over previous
//
#include <hip/hip_runtime.h>
#include <stdint.h>

// SpatialHyperedgeMP: out = ((inc + head) @ cur) / rowsum(inc + head)
//   head_ij = (inc_ij > 0) / sqrt(cnt_i),  cnt_i = #positives in row i
// Decomposition (single fused pass over inc):
//   out[i] = (inc@cur + invs_i * (mask@cur)) * rdeg_i
//   invs_i = 1/sqrt(cnt_i),  rdeg_i = 1/(s1_i + sqrt(cnt_i))
//
// R10: recombination of proven elements only.
//   - BM=32 BN=256 nt=2 (B-L2 system traffic = (M/BM)*8MB = 2GB; BM16 was 4GB -> R9 477us)
//   - 512-thr 8-wave blocks, 2 blk/CU -> 4 waves/SIMD (occupancy)
//   - B direct ws->reg, FULL-TILE double buffered (R7's proven piece; no B LDS -> DS diet)
//   - A staged as RAW fp32 via async global_load_lds (no pre-transform needed);
//     frags built in-reg from LDS (XOR source-swizzle, 2-way-free reads)
//   - ONE barrier + ONE counted vmcnt(4) per tile: FIFO [A_lds:1, B_next:4],
//     vmcnt(4) retires A only; B rides through the barrier (T4)
//   - stats (fp64 s1, int cnt) on wave 0 only: each A element counted exactly once
//
// ws usage: 8MB B chunks only.

#define NROWS 8192
#define DDIM  512

typedef float f32x4 __attribute__((ext_vector_type(4)));
typedef short s16x8 __attribute__((ext_vector_type(8)));

__device__ __forceinline__ unsigned short f2bf(float f) {
  union { float f; unsigned int u; } c; c.f = f;
  unsigned int u = c.u;
  unsigned int r = u + 0x7FFFu + ((u >> 16) & 1u);
  return (unsigned short)(r >> 16);
}

// ---------------- kernel 1: B prep (cur -> bf16 chunked-transposed) ----------------
// chunk layout: nt(2) x kt(128): 32KB chunk = [kg=8][nn=256][e=8] bf16
__global__ __launch_bounds__(256) void bprep_kernel(const float* __restrict__ cur,
                                                    unsigned char* __restrict__ bws) {
  int idx = blockIdx.x * 256 + threadIdx.x;  // 0..524287
  int n = idx & 511;
  int kg9 = idx >> 9;  // 0..1023
  int kt = kg9 >> 3;
  int kg = kg9 & 7;
  int k0 = kt * 64 + kg * 8;
  union { unsigned short h[8]; uint4 q; } u;
#pragma unroll
  for (int e = 0; e < 8; ++e)
    u.h[e] = f2bf(cur[(size_t)(k0 + e) * DDIM + n]);
  int nt = n >> 8, nn = n & 255;
  size_t off = ((size_t)(nt * 128 + kt) << 15) + ((size_t)kg << 12) + ((size_t)nn << 4);
  *(uint4*)(bws + off) = u.q;
}

// ---------------- kernel 2: fused stats + dual-GEMM ----------------
// BM=32 BN=256 BK=64, 512 thr = 8 waves, wave tile 32x32 (wv = column group).
// LDS: A raw fp32 dbuf 2x8KB (layout [row 32][slot 16] float4, source-swizzled
// slot = sp ^ ((row&7)<<1)) + 512B stats. Total 16.9KB.

#define FENCE() __builtin_amdgcn_sched_barrier(0)
#define BARRIER() __builtin_amdgcn_s_barrier()
#define WAITVM4() asm volatile("s_waitcnt vmcnt(4)" ::: "memory")
#define MFMA_ __builtin_amdgcn_mfma_f32_16x16x32_bf16

__global__ __launch_bounds__(512, 4) void gemm_kernel(const float* __restrict__ inc,
                                                      const unsigned char* __restrict__ bws,
                                                      float* __restrict__ out) {
  __shared__ __align__(16) unsigned char smem[16896];
  unsigned char* const aBuf0 = smem;
  unsigned char* const aBuf1 = smem + 8192;
  float* const statS = (float*)(smem + 16384);  // invs[32], rdeg[32]

  const int tid = threadIdx.x;
  const int lane = tid & 63;
  const int wv = tid >> 6;       // 0..7 column group
  const int r = lane & 15;
  const int q = lane >> 4;       // 0..3

  const int id = blockIdx.x;     // 0..511
  const int nt = id & 1;         // XCD parity -> B chunk L2-resident
  const int mt = id >> 1;        // nt-partners adjacent -> L3 dedups A (proven)
  const int brow = mt * 32;

  // ---- A staging map (async global_load_lds; source pre-swizzled) ----
  const int sm = tid >> 4;       // row 0..31
  const int sp = tid & 15;       // stored float4 slot
  const int ssp = sp ^ ((sm & 7) << 1);   // source slot (even XOR keeps b128 pairs)
  const float* gA = inc + (size_t)(brow + sm) * NROWS + ssp * 4;
  const int ldsWave = wv << 10;  // wave-uniform dest: 64 lanes x 16B

  // ---- A frag read offsets: frag(kh,rg): rows rg*16+r, orig slots kh*8+q*2,+1 ----
  int aOff[2][2];
#pragma unroll
  for (int kh = 0; kh < 2; ++kh)
#pragma unroll
    for (int rg = 0; rg < 2; ++rg) {
      int row = rg * 16 + r;
      int s0 = (kh * 8 + q * 2) ^ ((row & 7) << 1);
      aOff[kh][rg] = row * 256 + (s0 << 4);
    }

  // ---- B frag offsets (direct from ws) ----
  const unsigned char* gB = bws + ((size_t)(nt * 128) << 15);
  int bOff[2][2];  // [kh][cg]
#pragma unroll
  for (int kh = 0; kh < 2; ++kh)
#pragma unroll
    for (int cg = 0; cg < 2; ++cg)
      bOff[kh][cg] = ((kh * 4 + q) << 12) + ((wv * 32 + cg * 16 + r) << 4);

  f32x4 acc1[2][2], acc2[2][2];
#pragma unroll
  for (int a = 0; a < 2; ++a)
#pragma unroll
    for (int b = 0; b < 2; ++b) {
      acc1[a][b] = (f32x4){0.f, 0.f, 0.f, 0.f};
      acc2[a][b] = (f32x4){0.f, 0.f, 0.f, 0.f};
    }

  double s1r[2] = {0.0, 0.0};
  int cnt[2] = {0, 0};
  const bool statw = (wv == 0);  // wave 0 covers rows r,r+16 x all k exactly once

  s16x8 bX[4], bY[4];            // B frag double reg-buffer [kh*2+cg]

#define ISSUE_A(KT, BUF)                                                                  \
  __builtin_amdgcn_global_load_lds(                                                       \
      (const __attribute__((address_space(1))) unsigned int*)(gA + (size_t)(KT) * 64),    \
      (__attribute__((address_space(3))) unsigned int*)((BUF) + ldsWave), 16, 0, 0)

#define LOADB(BS, KT) do {                                                                \
    const unsigned char* _g = gB + ((size_t)(KT) << 15);                                  \
    BS[0] = *(const s16x8*)(_g + bOff[0][0]);                                             \
    BS[1] = *(const s16x8*)(_g + bOff[0][1]);                                             \
    BS[2] = *(const s16x8*)(_g + bOff[1][0]);                                             \
    BS[3] = *(const s16x8*)(_g + bOff[1][1]);                                             \
  } while (0)

#define MKFRAG(lo, hi, AF, MF) do {                                                       \
    union { unsigned u[4]; s16x8 s; } _a, _m;                                             \
    asm("v_cvt_pk_bf16_f32 %0, %1, %2" : "=v"(_a.u[0]) : "v"(lo[0]), "v"(lo[1]));         \
    asm("v_cvt_pk_bf16_f32 %0, %1, %2" : "=v"(_a.u[1]) : "v"(lo[2]), "v"(lo[3]));         \
    asm("v_cvt_pk_bf16_f32 %0, %1, %2" : "=v"(_a.u[2]) : "v"(hi[0]), "v"(hi[1]));         \
    asm("v_cvt_pk_bf16_f32 %0, %1, %2" : "=v"(_a.u[3]) : "v"(hi[2]), "v"(hi[3]));         \
    _m.u[0] = (lo[0] > 0.f ? 0x3F80u : 0u) | (lo[1] > 0.f ? 0x3F800000u : 0u);            \
    _m.u[1] = (lo[2] > 0.f ? 0x3F80u : 0u) | (lo[3] > 0.f ? 0x3F800000u : 0u);            \
    _m.u[2] = (hi[0] > 0.f ? 0x3F80u : 0u) | (hi[1] > 0.f ? 0x3F800000u : 0u);            \
    _m.u[3] = (hi[2] > 0.f ? 0x3F80u : 0u) | (hi[3] > 0.f ? 0x3F800000u : 0u);            \
    AF = _a.s; MF = _m.s;                                                                 \
  } while (0)

#define KHALF(ABUF, BS, kh) do {                                                          \
    f32x4 ra0 = *(const f32x4*)((ABUF) + aOff[kh][0]);                                    \
    f32x4 ra1 = *(const f32x4*)((ABUF) + aOff[kh][0] + 16);                               \
    f32x4 rb0 = *(const f32x4*)((ABUF) + aOff[kh][1]);                                    \
    f32x4 rb1 = *(const f32x4*)((ABUF) + aOff[kh][1] + 16);                               \
    if (statw) {                                                                          \
      s1r[0] += (double)((ra0[0] + ra0[1]) + (ra0[2] + ra0[3]));                          \
      s1r[0] += (double)((ra1[0] + ra1[1]) + (ra1[2] + ra1[3]));                          \
      s1r[1] += (double)((rb0[0] + rb0[1]) + (rb0[2] + rb0[3]));                          \
      s1r[1] += (double)((rb1[0] + rb1[1]) + (rb1[2] + rb1[3]));                          \
      cnt[0] += (ra0[0] > 0.f) + (ra0[1] > 0.f) + (ra0[2] > 0.f) + (ra0[3] > 0.f)         \
              + (ra1[0] > 0.f) + (ra1[1] > 0.f) + (ra1[2] > 0.f) + (ra1[3] > 0.f);        \
      cnt[1] += (rb0[0] > 0.f) + (rb0[1] > 0.f) + (rb0[2] > 0.f) + (rb0[3] > 0.f)         \
              + (rb1[0] > 0.f) + (rb1[1] > 0.f) + (rb1[2] > 0.f) + (rb1[3] > 0.f);        \
    }                                                                                     \
    s16x8 af0, mf0, af1, mf1;                                                             \
    MKFRAG(ra0, ra1, af0, mf0);                                                           \
    MKFRAG(rb0, rb1, af1, mf1);                                                           \
    __builtin_amdgcn_s_setprio(1);                                                        \
    acc1[0][0] = MFMA_(af0, BS[kh * 2 + 0], acc1[0][0], 0, 0, 0);                         \
    acc2[0][0] = MFMA_(mf0, BS[kh * 2 + 0], acc2[0][0], 0, 0, 0);                         \
    acc1[0][1] = MFMA_(af0, BS[kh * 2 + 1], acc1[0][1], 0, 0, 0);                         \
    acc2[0][1] = MFMA_(mf0, BS[kh * 2 + 1], acc2[0][1], 0, 0, 0);                         \
    acc1[1][0] = MFMA_(af1, BS[kh * 2 + 0], acc1[1][0], 0, 0, 0);                         \
    acc2[1][0] = MFMA_(mf1, BS[kh * 2 + 0], acc2[1][0], 0, 0, 0);                         \
    acc1[1][1] = MFMA_(af1, BS[kh * 2 + 1], acc1[1][1], 0, 0, 0);                         \
    acc2[1][1] = MFMA_(mf1, BS[kh * 2 + 1], acc2[1][1], 0, 0, 0);                         \
    __builtin_amdgcn_s_setprio(0);                                                        \
  } while (0)

#define TILE(ABUF, BS) do { KHALF(ABUF, BS, 0); KHALF(ABUF, BS, 1); } while (0)

  // ---- prologue: A(0)->buf0 staged, B(0)->bX in flight ----
  ISSUE_A(0, aBuf0);
  FENCE();
  LOADB(bX, 0);
  FENCE();
  WAITVM4();             // FIFO [A0:1, B0:4] -> retire A0 only
  BARRIER();
  FENCE();

  // ---- steady: unrolled by 2 for static buffer/reg names ----
  for (int kt = 0; kt < 126; kt += 2) {
    ISSUE_A(kt + 1, aBuf1);
    FENCE();
    LOADB(bY, kt + 1);
    FENCE();
    TILE(aBuf0, bX);     // compiler auto-waits B(kt) precisely
    FENCE();
    WAITVM4();           // FIFO [A(kt+1):1, B(kt+1):4] -> retire A only
    BARRIER();
    FENCE();
    ISSUE_A(kt + 2, aBuf0);
    FENCE();
    LOADB(bX, kt + 2);
    FENCE();
    TILE(aBuf1, bY);
    FENCE();
    WAITVM4();
    BARRIER();
    FENCE();
  }
  // ---- tail: tiles 126, 127 ----
  ISSUE_A(127, aBuf1);
  FENCE();
  LOADB(bY, 127);
  FENCE();
  TILE(aBuf0, bX);
  FENCE();
  WAITVM4();
  BARRIER();
  FENCE();
  TILE(aBuf1, bY);

  // ---- stats: reduce wave 0 over q (lanes r, r+16, r+32, r+48) ----
  if (statw) {
#pragma unroll
    for (int g = 0; g < 2; ++g) {
      s1r[g] += __shfl_xor(s1r[g], 16);
      s1r[g] += __shfl_xor(s1r[g], 32);
      cnt[g] += __shfl_xor(cnt[g], 16);
      cnt[g] += __shfl_xor(cnt[g], 32);
    }
    if (q == 0) {
      double sq0 = sqrt((double)cnt[0]);
      double sq1 = sqrt((double)cnt[1]);
      statS[r]      = (cnt[0] > 0) ? (float)(1.0 / sq0) : 0.0f;   // invs row r
      statS[16 + r] = (cnt[1] > 0) ? (float)(1.0 / sq1) : 0.0f;   // invs row r+16
      statS[32 + r]      = (float)(1.0 / (s1r[0] + sq0));         // rdeg row r
      statS[48 + r]      = (float)(1.0 / (s1r[1] + sq1));         // rdeg row r+16
    }
  }
  __syncthreads();

  // ---- epilogue: (acc1 + invs*acc2) * rdeg ----
  const float* invsS = statS;
  const float* rdegS = statS + 32;
#pragma unroll
  for (int rg = 0; rg < 2; ++rg) {
#pragma unroll
    for (int cg = 0; cg < 2; ++cg) {
#pragma unroll
      for (int j = 0; j < 4; ++j) {
        int row = rg * 16 + q * 4 + j;
        out[(size_t)(brow + row) * DDIM + nt * 256 + wv * 32 + cg * 16 + r] =
            (acc1[rg][cg][j] + invsS[row] * acc2[rg][cg][j]) * rdegS[row];
      }
    }
  }
#undef ISSUE_A
#undef LOADB
#undef MKFRAG
#undef KHALF
#undef TILE
}

extern "C" void kernel_launch(void* const* d_in, const int* in_sizes, int n_in,
                              void* d_out, int out_size, void* d_ws, size_t ws_size,
                              hipStream_t stream) {
  const float* cur = (const float*)d_in[0];          // [8192, 512] fp32
  const float* incm = (const float*)d_in[1];         // [8192, 8192] fp32
  float* out = (float*)d_out;                        // [8192, 512] fp32
  unsigned char* bws = (unsigned char*)d_ws;         // 8MB B chunks

  hipLaunchKernelGGL(bprep_kernel, dim3((NROWS * DDIM / 8) / 256), dim3(256), 0, stream,
                     cur, bws);
  hipLaunchKernelGGL(gemm_kernel, dim3(512), dim3(512), 0, stream, incm, bws, out);
}

// Round 11
// 166.941 us; speedup vs baseline: 2.6679x; 1.3302x over previous
//
#include <hip/hip_runtime.h>
#include <stdint.h>

// SpatialHyperedgeMP: out = ((inc + head) @ cur) / rowsum(inc + head)
//   head_ij = (inc_ij > 0) / sqrt(cnt_i),  cnt_i = #positives in row i
// Decomposition (single fused pass over inc):
//   out[i] = (inc@cur + invs_i * (mask@cur)) * rdeg_i
//   invs_i = 1/sqrt(cnt_i),  rdeg_i = 1/(s1_i + sqrt(cnt_i))
//
// R11 = R7's proven pipeline ⊕ 8-wave blocks (R10's occupancy).
//   - A+M staged PRE-CONVERTED bf16 in LDS (transform once per element by the
//     staging thread; R10's raw-fp32 variant duplicated cvt 8x and conflicted).
//   - A/M LDS layout [kg=8][slot=32][16B], slot=row^kg: measured 0 conflicts (R5-R7).
//   - B direct ws->reg, double-buffered (DS diet, R7). No manual vmcnt needed:
//     register deps give precise compiler waits; only lgkmcnt(0)+barrier per tile.
//   - 512 thr = 8 waves (wave tile 32x32), grid 512 = 2 blk/CU = 4 waves/SIMD.
//   - nt pinned to XCD half (id&7)>=4: each XCD L2 streams ONE 4MB B chunk;
//     mt-partners are id,id^4 -> adjacent dispatch -> L3 dedups A.
//   - stats fp64/int accumulated by the staging thread (each element once).
//
// ws usage: 8MB B chunks only.

#define NROWS 8192
#define DDIM  512

typedef float f32x4 __attribute__((ext_vector_type(4)));
typedef short s16x8 __attribute__((ext_vector_type(8)));

__device__ __forceinline__ unsigned short f2bf(float f) {
  union { float f; unsigned int u; } c; c.f = f;
  unsigned int u = c.u;
  unsigned int r = u + 0x7FFFu + ((u >> 16) & 1u);
  return (unsigned short)(r >> 16);
}

// ---------------- kernel 1: B prep (cur -> bf16 chunked-transposed) ----------------
// chunk layout: nt(2) x kt(128): 32KB chunk = [kg=8][nn=256][e=8] bf16
__global__ __launch_bounds__(256) void bprep_kernel(const float* __restrict__ cur,
                                                    unsigned char* __restrict__ bws) {
  int idx = blockIdx.x * 256 + threadIdx.x;  // 0..524287
  int n = idx & 511;
  int kg9 = idx >> 9;  // 0..1023
  int kt = kg9 >> 3;
  int kg = kg9 & 7;
  int k0 = kt * 64 + kg * 8;
  union { unsigned short h[8]; uint4 q; } u;
#pragma unroll
  for (int e = 0; e < 8; ++e)
    u.h[e] = f2bf(cur[(size_t)(k0 + e) * DDIM + n]);
  int nt = n >> 8, nn = n & 255;
  size_t off = ((size_t)(nt * 128 + kt) << 15) + ((size_t)kg << 12) + ((size_t)nn << 4);
  *(uint4*)(bws + off) = u.q;
}

// ---------------- kernel 2: fused stats + dual-GEMM ----------------
// BM=32 BN=256 BK=64, 512 thr = 8 waves (1M x 8N), wave tile 32x32.
// LDS (16.2KB): {A 4KB + M 4KB} x dbuf; stats reuse buf0 after K-loop.

#define FENCE() __builtin_amdgcn_sched_barrier(0)
#define BARRIER() __builtin_amdgcn_s_barrier()
#define WAITLGKM() asm volatile("s_waitcnt lgkmcnt(0)" ::: "memory")
#define MFMA_ __builtin_amdgcn_mfma_f32_16x16x32_bf16

__global__ __launch_bounds__(512, 4) void gemm_kernel(const float* __restrict__ inc,
                                                      const unsigned char* __restrict__ bws,
                                                      float* __restrict__ out) {
  __shared__ __align__(16) unsigned char smem[16512];
  unsigned char* const buf0 = smem;          // A @0, M @+4096
  unsigned char* const buf1 = smem + 8192;

  const int tid = threadIdx.x;
  const int lane = tid & 63;
  const int wv = tid >> 6;       // 0..7 column group
  const int r = lane & 15;
  const int q = lane >> 4;       // 0..3

  const int id = blockIdx.x;     // 0..511
  const int nt = (id & 7) >> 2;  // XCD half -> fixed 4MB B chunk per XCD L2
  const int mt = (id >> 3) * 4 + (id & 3);   // 0..255; partners id,id^4 adjacent
  const int brow = mt * 32;

  // ---- A staging ownership: thread -> (row sm, float4-slot sp) ----
  const int sm = tid >> 4;       // 0..31
  const int sp = tid & 15;       // 0..15 (k = sp*4..sp*4+3)
  const int kgw = sp >> 1, half = sp & 1;
  const float4* gAr = (const float4*)(inc + (size_t)(brow + sm) * NROWS) + sp;
  const int aWr = (kgw << 9) + ((sm ^ kgw) << 4) + (half << 3);

  // ---- A/M frag LDS offsets: frag(kh,rg): kg=kh*4+q, row=rg*16+r ----
  int aOff[2][2];
#pragma unroll
  for (int kh = 0; kh < 2; ++kh)
#pragma unroll
    for (int rg = 0; rg < 2; ++rg) {
      int kg = kh * 4 + q;
      int row = rg * 16 + r;
      aOff[kh][rg] = (kg << 9) + ((row ^ kg) << 4);
    }

  // ---- B frag ws offsets (within 32KB kt-chunk) ----
  const unsigned char* gB = bws + ((size_t)(nt * 128) << 15);
  int bOff[4];  // [kh*2+cg]
#pragma unroll
  for (int kh = 0; kh < 2; ++kh)
#pragma unroll
    for (int cg = 0; cg < 2; ++cg)
      bOff[kh * 2 + cg] = ((kh * 4 + q) << 12) + ((wv * 32 + cg * 16 + r) << 4);

  f32x4 acc1[2][2], acc2[2][2];
#pragma unroll
  for (int a = 0; a < 2; ++a)
#pragma unroll
    for (int b = 0; b < 2; ++b) {
      acc1[a][b] = (f32x4){0.f, 0.f, 0.f, 0.f};
      acc2[a][b] = (f32x4){0.f, 0.f, 0.f, 0.f};
    }

  double s1 = 0.0;
  int cnt = 0;
  float4 x, y;
  s16x8 bX[4], bY[4];

#define ISSUE_A(d, KT) do { d = gAr[(KT) * 16]; } while (0)

#define LOADB(BS, KT) do {                                                                \
    const unsigned char* _g = gB + ((size_t)(KT) << 15);                                  \
    BS[0] = *(const s16x8*)(_g + bOff[0]);                                                \
    BS[1] = *(const s16x8*)(_g + bOff[1]);                                                \
    BS[2] = *(const s16x8*)(_g + bOff[2]);                                                \
    BS[3] = *(const s16x8*)(_g + bOff[3]);                                                \
  } while (0)

// stage one float4: exact stats + bf16 A + bf16 mask -> LDS (b64 each)
#define XFORM(v, BUF) do {                                                                \
    s1 += (double)v.x + (double)v.y + (double)v.z + (double)v.w;                          \
    cnt += (v.x > 0.f) + (v.y > 0.f) + (v.z > 0.f) + (v.w > 0.f);                         \
    unsigned dlo, dhi;                                                                    \
    asm("v_cvt_pk_bf16_f32 %0, %1, %2" : "=v"(dlo) : "v"(v.x), "v"(v.y));                 \
    asm("v_cvt_pk_bf16_f32 %0, %1, %2" : "=v"(dhi) : "v"(v.z), "v"(v.w));                 \
    unsigned mlo = (v.x > 0.f ? 0x3F80u : 0u) | (v.y > 0.f ? 0x3F800000u : 0u);           \
    unsigned mhi = (v.z > 0.f ? 0x3F80u : 0u) | (v.w > 0.f ? 0x3F800000u : 0u);           \
    *(unsigned long long*)((BUF) + aWr) =                                                 \
        (unsigned long long)dlo | ((unsigned long long)dhi << 32);                        \
    *(unsigned long long*)((BUF) + 4096 + aWr) =                                          \
        (unsigned long long)mlo | ((unsigned long long)mhi << 32);                        \
  } while (0)

#define MFMA_TILE(BUF, BS) do {                                                           \
    _Pragma("unroll")                                                                     \
    for (int kh = 0; kh < 2; ++kh) {                                                      \
      s16x8 af0 = *(const s16x8*)((BUF) + aOff[kh][0]);                                   \
      s16x8 af1 = *(const s16x8*)((BUF) + aOff[kh][1]);                                   \
      s16x8 mf0 = *(const s16x8*)((BUF) + 4096 + aOff[kh][0]);                            \
      s16x8 mf1 = *(const s16x8*)((BUF) + 4096 + aOff[kh][1]);                            \
      __builtin_amdgcn_s_setprio(1);                                                      \
      acc1[0][0] = MFMA_(af0, BS[kh * 2 + 0], acc1[0][0], 0, 0, 0);                       \
      acc2[0][0] = MFMA_(mf0, BS[kh * 2 + 0], acc2[0][0], 0, 0, 0);                       \
      acc1[0][1] = MFMA_(af0, BS[kh * 2 + 1], acc1[0][1], 0, 0, 0);                       \
      acc2[0][1] = MFMA_(mf0, BS[kh * 2 + 1], acc2[0][1], 0, 0, 0);                       \
      acc1[1][0] = MFMA_(af1, BS[kh * 2 + 0], acc1[1][0], 0, 0, 0);                       \
      acc2[1][0] = MFMA_(mf1, BS[kh * 2 + 0], acc2[1][0], 0, 0, 0);                       \
      acc1[1][1] = MFMA_(af1, BS[kh * 2 + 1], acc1[1][1], 0, 0, 0);                       \
      acc2[1][1] = MFMA_(mf1, BS[kh * 2 + 1], acc2[1][1], 0, 0, 0);                       \
      __builtin_amdgcn_s_setprio(0);                                                      \
    }                                                                                     \
  } while (0)

#define SYNC() do { FENCE(); WAITLGKM(); FENCE(); BARRIER(); FENCE(); } while (0)

  // ---- prologue ----
  ISSUE_A(x, 0);
  LOADB(bX, 0);
  ISSUE_A(y, 1);
  XFORM(x, buf0);                // compiler waits x precisely, leaves bX/y in flight
  SYNC();

  // ---- steady: tiles 0..125, unrolled by 2 ----
  for (int kt = 0; kt < 126; kt += 2) {
    ISSUE_A(x, kt + 2);
    LOADB(bY, kt + 1);
    FENCE();                     // pin load issue above the MFMA cluster
    MFMA_TILE(buf0, bX);
    XFORM(y, buf1);
    SYNC();
    ISSUE_A(y, kt + 3);
    LOADB(bX, kt + 2);
    FENCE();
    MFMA_TILE(buf1, bY);
    XFORM(x, buf0);
    SYNC();
  }

  // ---- tail: tiles 126, 127 ----
  LOADB(bY, 127);
  FENCE();
  MFMA_TILE(buf0, bX);
  XFORM(y, buf1);                // A(127)
  SYNC();
  MFMA_TILE(buf1, bY);

  // ---- stats: reduce over sp (16 consecutive lanes share row sm) ----
#pragma unroll
  for (int o = 1; o < 16; o <<= 1) {
    s1 += __shfl_xor(s1, o);
    cnt += __shfl_xor(cnt, o);
  }
  __syncthreads();               // everyone past buf0 reads -> reuse as stats
  float* const invsS = (float*)buf0;    // 32 floats
  float* const rdegS = invsS + 32;      // 32 floats
  if (sp == 0) {
    double sq = sqrt((double)cnt);
    invsS[sm] = (cnt > 0) ? (float)(1.0 / sq) : 0.0f;
    rdegS[sm] = (float)(1.0 / (s1 + sq));
  }
  __syncthreads();

  // ---- epilogue: (acc1 + invs*acc2) * rdeg ----
#pragma unroll
  for (int rg = 0; rg < 2; ++rg) {
#pragma unroll
    for (int cg = 0; cg < 2; ++cg) {
#pragma unroll
      for (int j = 0; j < 4; ++j) {
        int row = rg * 16 + q * 4 + j;
        out[(size_t)(brow + row) * DDIM + nt * 256 + wv * 32 + cg * 16 + r] =
            (acc1[rg][cg][j] + invsS[row] * acc2[rg][cg][j]) * rdegS[row];
      }
    }
  }
#undef ISSUE_A
#undef LOADB
#undef XFORM
#undef MFMA_TILE
#undef SYNC
}

extern "C" void kernel_launch(void* const* d_in, const int* in_sizes, int n_in,
                              void* d_out, int out_size, void* d_ws, size_t ws_size,
                              hipStream_t stream) {
  const float* cur = (const float*)d_in[0];          // [8192, 512] fp32
  const float* incm = (const float*)d_in[1];         // [8192, 8192] fp32
  float* out = (float*)d_out;                        // [8192, 512] fp32
  unsigned char* bws = (unsigned char*)d_ws;         // 8MB B chunks

  hipLaunchKernelGGL(bprep_kernel, dim3((NROWS * DDIM / 8) / 256), dim3(256), 0, stream,
                     cur, bws);
  hipLaunchKernelGGL(gemm_kernel, dim3(512), dim3(512), 0, stream, incm, bws, out);
}